// Round 1
// baseline (114.641 us; speedup 1.0000x reference)
//
#include <hip/hip_runtime.h>
#include <math.h>

// Problem constants (from reference setup_inputs): B=4, C_in=512, N=4096, OUT=256.
// Key insight: softmax is over a singleton axis -> coefs == 1 everywhere, so
//   out[b,o,0,n] = elu( sum_c W1[o,c] * sum_n x[b,c,0,n] )   (constant over n).
#define NN   4096
#define CIN  512
#define COUT 256
#define BB   4

// One block per (b,c) row: reduce 4096 floats -> xs[b*CIN+c].
__global__ __launch_bounds__(256) void row_sum_kernel(const float* __restrict__ x,
                                                      float* __restrict__ xs) {
    const int row = blockIdx.x;                       // 0 .. B*CIN-1
    const float4* p = (const float4*)(x + (size_t)row * NN);
    const int t = threadIdx.x;                        // 0..255
    float s = 0.f;
    // 4096 floats = 1024 float4; 256 threads * 4 each, coalesced.
    #pragma unroll
    for (int i = 0; i < 4; ++i) {
        float4 v = p[t + i * 256];
        s += (v.x + v.y) + (v.z + v.w);
    }
    // wave64 shuffle reduce, then LDS across the 4 waves
    #pragma unroll
    for (int off = 32; off; off >>= 1) s += __shfl_down(s, off, 64);
    __shared__ float wsum[4];
    const int wave = t >> 6, lane = t & 63;
    if (lane == 0) wsum[wave] = s;
    __syncthreads();
    if (t == 0) xs[row] = (wsum[0] + wsum[1]) + (wsum[2] + wsum[3]);
}

// One block per (b,o): dot(W1[o,:], xs[b,:]) over 512, elu, broadcast 4096 writes.
__global__ __launch_bounds__(256) void gemv_elu_bcast_kernel(const float* __restrict__ W1,
                                                             const float* __restrict__ xs,
                                                             float* __restrict__ out) {
    const int blk = blockIdx.x;                       // b*COUT + o
    const int b = blk >> 8;                           // COUT == 256
    const int o = blk & 255;
    const int t = threadIdx.x;
    const float* w = W1 + (size_t)o * CIN;
    const float* v = xs + (size_t)b * CIN;
    float s = w[t] * v[t] + w[t + 256] * v[t + 256];
    #pragma unroll
    for (int off = 32; off; off >>= 1) s += __shfl_down(s, off, 64);
    __shared__ float wsum[4];
    const int wave = t >> 6, lane = t & 63;
    if (lane == 0) wsum[wave] = s;
    __syncthreads();
    const float S = (wsum[0] + wsum[1]) + (wsum[2] + wsum[3]);
    const float e = (S > 0.f) ? S : (expf(S) - 1.f);
    float4 val = make_float4(e, e, e, e);
    float4* po = (float4*)(out + (size_t)blk * NN);
    #pragma unroll
    for (int i = 0; i < 4; ++i) po[t + i * 256] = val;
}

extern "C" void kernel_launch(void* const* d_in, const int* in_sizes, int n_in,
                              void* d_out, int out_size, void* d_ws, size_t ws_size,
                              hipStream_t stream) {
    const float* x  = (const float*)d_in[0];   // [B, CIN, 1, N]
    const float* W1 = (const float*)d_in[1];   // [COUT, CIN]
    // d_in[2] (w2) and d_in[3] (bias_mat) are dead: softmax over singleton axis.
    float* out = (float*)d_out;                // [B, COUT, 1, N]
    float* xs  = (float*)d_ws;                 // B*CIN floats = 8 KB scratch

    row_sum_kernel<<<BB * CIN, 256, 0, stream>>>(x, xs);
    gemv_elu_bcast_kernel<<<BB * COUT, 256, 0, stream>>>(W1, xs, out);
}